// Round 12
// baseline (254.310 us; speedup 1.0000x reference)
//
#include <hip/hip_runtime.h>

typedef unsigned short u16;
typedef _Float16 f16x8 __attribute__((ext_vector_type(8)));
typedef short bf16x8 __attribute__((ext_vector_type(8)));
typedef float f32x16 __attribute__((ext_vector_type(16)));
typedef unsigned int u32x4 __attribute__((ext_vector_type(4)));
typedef unsigned int u32x2 __attribute__((ext_vector_type(2)));

#define LOG2E 1.44269504088896340736f

static __device__ __forceinline__ u16 f2h(float f){
  union { _Float16 h; u16 u; } v; v.h = (_Float16)f; return v.u;
}
static __device__ __forceinline__ u16 f2bf(float f){
  union { float f; unsigned u; } v; v.f = f;
  return (u16)((v.u + 0x7fffu + ((v.u >> 16) & 1u)) >> 16);
}
static __device__ __forceinline__ unsigned pk2bf(float lo, float hi){
  unsigned r; asm("v_cvt_pk_bf16_f32 %0, %1, %2" : "=v"(r) : "v"(lo), "v"(hi)); return r;
}
static __device__ __forceinline__ float ex2(float x){
#if __has_builtin(__builtin_amdgcn_exp2f)
  return __builtin_amdgcn_exp2f(x);
#else
  return exp2f(x);
#endif
}
#define PSWAP(a, b) asm("v_permlane32_swap_b32 %0, %1" : "+v"(a), "+v"(b))

// B=8, C=512, N=4096, MID=64
// ---------------- kernel 0: x[b][c][n] f32 -> xt[b][n][c] f16 ----------------
__global__ __launch_bounds__(256) void k_tr(const float* __restrict__ x, u16* __restrict__ xt){
  int bx = blockIdx.x;
  int nb = bx & 63, cb = (bx >> 6) & 7, b = bx >> 9;
  __shared__ u16 lt[64 * 68];
  int t = threadIdx.x;
  int cl = t >> 4, n0 = (t & 15) * 4;
  const float* xp = x + ((size_t)(b * 512 + cb * 64)) * 4096 + nb * 64;
#pragma unroll
  for (int i = 0; i < 4; ++i) {
    int c = cl + i * 16;
    float4 v = *(const float4*)(xp + (size_t)c * 4096 + n0);
    u16* d = &lt[c * 68 + n0];
    d[0] = f2h(v.x); d[1] = f2h(v.y); d[2] = f2h(v.z); d[3] = f2h(v.w);
  }
  __syncthreads();
  u16* xo = xt + ((size_t)(b * 4096 + nb * 64)) * 512 + cb * 64;
#pragma unroll
  for (int i = 0; i < 2; ++i) {
    int s = t + i * 256;
    int n = s >> 3, ch = s & 7;
    u32x4 o;
#pragma unroll
    for (int j = 0; j < 4; ++j) {
      u16 a = lt[(ch * 8 + 2 * j) * 68 + n];
      u16 bb = lt[(ch * 8 + 2 * j + 1) * 68 + n];
      o[j] = (unsigned)a | ((unsigned)bb << 16);
    }
    *(u32x4*)(xo + (size_t)n * 512 + ch * 8) = o;
  }
}

// ------------- kernel 1: qk[b][n][0..64)=Q=Xt*(LOG2E*Wb)^T, [64..128)=K=Xt*Wc^T -------------
__global__ __launch_bounds__(512) void k_pqk(const u16* __restrict__ xt, const float* __restrict__ wb,
                                             const float* __restrict__ wc, u16* __restrict__ qk){
  int bx = blockIdx.x;
  int nb = bx & 31, b = bx >> 5;
  __shared__ u16 lx[128 * 64];
  __shared__ u16 lw[128 * 64];
  int t = threadIdx.x, w = t >> 6, l = t & 63, hi = l >> 5, ln = l & 31;
  int wr = w >> 1, wcol = w & 1;
  f32x16 acc[2] = {};
  for (int kt = 0; kt < 8; ++kt) {
    int c0 = kt * 64;
#pragma unroll
    for (int i = 0; i < 2; ++i) {
      int s = t + i * 512; int row = s >> 3, ch = s & 7;
      u32x4 v = *(const u32x4*)(xt + ((size_t)(b * 4096 + nb * 128 + row)) * 512 + c0 + ch * 8);
      *(u32x4*)((char*)lx + ((row * 128 + ch * 16) ^ ((row & 7) << 4))) = v;
    }
#pragma unroll
    for (int i = 0; i < 4; ++i) {
      int s = t + i * 512; int row = s >> 4, c4 = s & 15;
      const float* src = (row < 64) ? (wb + (size_t)row * 512 + c0 + c4 * 4)
                                    : (wc + (size_t)(row - 64) * 512 + c0 + c4 * 4);
      float4 v = *(const float4*)src;
      float sc = (row < 64) ? LOG2E : 1.0f;
      unsigned lo = (unsigned)f2h(v.x * sc) | ((unsigned)f2h(v.y * sc) << 16);
      unsigned h2 = (unsigned)f2h(v.z * sc) | ((unsigned)f2h(v.w * sc) << 16);
      unsigned long long qv = ((unsigned long long)h2 << 32) | lo;
      *(unsigned long long*)((char*)lw + ((row * 128 + c4 * 8) ^ ((row & 7) << 4))) = qv;
    }
    __syncthreads();
#pragma unroll
    for (int cc = 0; cc < 4; ++cc) {
      int ra = wr * 32 + ln;
      f16x8 a = *(const f16x8*)((char*)lx + ((ra * 128 + cc * 32 + hi * 16) ^ ((ra & 7) << 4)));
#pragma unroll
      for (int mt = 0; mt < 2; ++mt) {
        int rb = wcol * 64 + mt * 32 + ln;
        f16x8 bb = *(const f16x8*)((char*)lw + ((rb * 128 + cc * 32 + hi * 16) ^ ((rb & 7) << 4)));
        acc[mt] = __builtin_amdgcn_mfma_f32_32x32x16_f16(a, bb, acc[mt], 0, 0, 0);
      }
    }
    __syncthreads();
  }
#pragma unroll
  for (int mt = 0; mt < 2; ++mt)
#pragma unroll
    for (int r = 0; r < 16; ++r) {
      int n = wr * 32 + (r & 3) + 8 * (r >> 2) + 4 * hi;
      int m = wcol * 64 + mt * 32 + ln;
      qk[((size_t)(b * 4096 + nb * 128 + n)) * 128 + m] = f2h(acc[mt][r]);
    }
}

// ------------- kernel 2: vt[b][o][n] = (Wd * Xt^T), bf16 output -------------
__global__ __launch_bounds__(512) void k_pv(const u16* __restrict__ xt, const float* __restrict__ wd,
                                            u16* __restrict__ vt){
  int bx = blockIdx.x;
  int nb = bx & 31, ob = (bx >> 5) & 3, b = bx >> 7;
  __shared__ u16 lx[128 * 64];
  __shared__ u16 lw[128 * 64];
  int t = threadIdx.x, w = t >> 6, l = t & 63, hi = l >> 5, ln = l & 31;
  int wr = w >> 2, wn = w & 3;
  f32x16 acc[2] = {};
  for (int kt = 0; kt < 8; ++kt) {
    int c0 = kt * 64;
#pragma unroll
    for (int i = 0; i < 2; ++i) {
      int s = t + i * 512; int row = s >> 3, ch = s & 7;
      u32x4 v = *(const u32x4*)(xt + ((size_t)(b * 4096 + nb * 128 + row)) * 512 + c0 + ch * 8);
      *(u32x4*)((char*)lx + ((row * 128 + ch * 16) ^ ((row & 7) << 4))) = v;
    }
#pragma unroll
    for (int i = 0; i < 4; ++i) {
      int s = t + i * 512; int row = s >> 4, c4 = s & 15;
      const float* src = wd + (size_t)(ob * 128 + row) * 512 + c0 + c4 * 4;
      float4 v = *(const float4*)src;
      unsigned lo = (unsigned)f2h(v.x) | ((unsigned)f2h(v.y) << 16);
      unsigned h2 = (unsigned)f2h(v.z) | ((unsigned)f2h(v.w) << 16);
      unsigned long long qv = ((unsigned long long)h2 << 32) | lo;
      *(unsigned long long*)((char*)lw + ((row * 128 + c4 * 8) ^ ((row & 7) << 4))) = qv;
    }
    __syncthreads();
#pragma unroll
    for (int cc = 0; cc < 4; ++cc) {
      int rb = wn * 32 + ln;
      f16x8 bb = *(const f16x8*)((char*)lx + ((rb * 128 + cc * 32 + hi * 16) ^ ((rb & 7) << 4)));
#pragma unroll
      for (int ot = 0; ot < 2; ++ot) {
        int ra = wr * 64 + ot * 32 + ln;
        f16x8 a = *(const f16x8*)((char*)lw + ((ra * 128 + cc * 32 + hi * 16) ^ ((ra & 7) << 4)));
        acc[ot] = __builtin_amdgcn_mfma_f32_32x32x16_f16(a, bb, acc[ot], 0, 0, 0);
      }
    }
    __syncthreads();
  }
#pragma unroll
  for (int ot = 0; ot < 2; ++ot)
#pragma unroll
    for (int r = 0; r < 16; ++r) {
      int o = ob * 128 + wr * 64 + ot * 32 + (r & 3) + 8 * (r >> 2) + 4 * hi;
      int n = nb * 128 + wn * 32 + ln;
      vt[((size_t)(b * 512 + o)) * 4096 + n] = f2bf(acc[ot][r]);
    }
}

// ------------- kernel 3: flash attention, o-chunk 256, 136B-stride LDS (conflict-free-ish) -------------
// P = exp2(S) directly, no max/stats. grid 256 XCD-chunked. 8 waves x 32 q; KV tile 64.
// LDS rows strided 136 B (dword-stride 34 = 2 mod 32): 8B-split reads give 2-way max (free, m136).
// Double buffer (2 x 42.5 KB), one barrier per iter. All LDS offsets in 8B units (provable align).
__global__ __launch_bounds__(512, 1) void k_attn2(const u16* __restrict__ qk, const u16* __restrict__ vt,
                                                  const float* __restrict__ x, const float* __restrict__ gamma,
                                                  float* __restrict__ out){
  __shared__ char smem[87040];   // buf[i] at i*43520: K 64x136 @+0 (8704B), V 256x136 @+8704 (34816B)
  int bx = blockIdx.x;
  int orig = (bx & 7) * 32 + (bx >> 3);
  int combo = orig >> 4, qt = orig & 15;
  int b = combo >> 1, oc2 = combo & 1;
  int obase = oc2 * 256;
  int t = threadIdx.x, w = t >> 6, l = t & 63, hi = l >> 5, ln = l & 31;
  int q = qt * 256 + w * 32 + ln;
  size_t b4096 = (size_t)b * 4096;
  // Q B-fragments (log2e folded in k_pqk)
  f16x8 qf[4];
  {
    const u16* qrow = qk + (b4096 + q) * 128;
#pragma unroll
    for (int ch = 0; ch < 4; ++ch) qf[ch] = *(const f16x8*)(qrow + ch * 16 + hi * 8);
  }
  // LDS addressing in 8B units: row r at r*17; frag (row=ln, colchunk) -> ln*17 + cc*4 + hi*2
  int rowS = t >> 3, chS = t & 7;
  unsigned w8 = (unsigned)(rowS * 17 + chS * 2);      // staging slot (8B units)
  unsigned rb8[4];
#pragma unroll
  for (int cc = 0; cc < 4; ++cc)
    rb8[cc] = (unsigned)(ln * 17 + cc * 4 + hi * 2);
  // global staging pointers
  const u16* gK = qk + (b4096 + rowS) * 128 + 64 + chS * 8;
  const u16* gV0 = vt + ((size_t)(b * 512 + obase + rowS)) * 4096 + chS * 8;
  const u16* gV1 = gV0 + (size_t)64 * 4096;
  const u16* gV2 = gV0 + (size_t)128 * 4096;
  const u16* gV3 = gV0 + (size_t)192 * 4096;
  u32x4 kreg = *(const u32x4*)gK;
  u32x4 vr0 = *(const u32x4*)gV0, vr1 = *(const u32x4*)gV1;
  u32x4 vr2 = *(const u32x4*)gV2, vr3 = *(const u32x4*)gV3;
  // prologue: write tile 0 into buf0 (V seg s lands at (1+s)*8704 + w8*8)
  {
    char* bp = smem;
    *(u32x2*)(bp + w8 * 8)              = u32x2{kreg[0], kreg[1]};
    *(u32x2*)(bp + w8 * 8 + 8)          = u32x2{kreg[2], kreg[3]};
    *(u32x2*)(bp + 8704  + w8 * 8)      = u32x2{vr0[0], vr0[1]};
    *(u32x2*)(bp + 8704  + w8 * 8 + 8)  = u32x2{vr0[2], vr0[3]};
    *(u32x2*)(bp + 17408 + w8 * 8)      = u32x2{vr1[0], vr1[1]};
    *(u32x2*)(bp + 17408 + w8 * 8 + 8)  = u32x2{vr1[2], vr1[3]};
    *(u32x2*)(bp + 26112 + w8 * 8)      = u32x2{vr2[0], vr2[1]};
    *(u32x2*)(bp + 26112 + w8 * 8 + 8)  = u32x2{vr2[2], vr2[3]};
    *(u32x2*)(bp + 34816 + w8 * 8)      = u32x2{vr3[0], vr3[1]};
    *(u32x2*)(bp + 34816 + w8 * 8 + 8)  = u32x2{vr3[2], vr3[3]};
  }
  gK += 8192; gV0 += 64; gV1 += 64; gV2 += 64; gV3 += 64;
  f32x16 acc[8] = {};
  float lacc = 0.0f;
  for (int kt = 0; kt < 64; ++kt) {
    __syncthreads();   // buf[kt&1] writes visible; prior reads of buf[(kt+1)&1] complete
    char* bufp = smem + (kt & 1) * 43520;
    char* bufn = smem + ((kt + 1) & 1) * 43520;
    if (kt < 63) {     // issue next-tile loads now; latency hides under this iter's compute
      kreg = *(const u32x4*)gK;
      vr0 = *(const u32x4*)gV0; vr1 = *(const u32x4*)gV1;
      vr2 = *(const u32x4*)gV2; vr3 = *(const u32x4*)gV3;
      gK += 8192; gV0 += 64; gV1 += 64; gV2 += 64; gV3 += 64;
    }
    // S^T = K * Q^T : lane holds 32 scores for q=ln (hi splits k 0-31 / 32-63)
    f32x16 s0 = {}, s1 = {};
    __builtin_amdgcn_s_setprio(1);
#pragma unroll
    for (int cc = 0; cc < 4; ++cc) {
      union { u32x2 d[2]; f16x8 v; } k0, k1;
      const char* p0 = bufp + rb8[cc] * 8;           // k rows 0-31
      const char* p1 = p0 + 4352;                    // k rows 32-63 (32*17*8)
      k0.d[0] = *(const u32x2*)p0;  k0.d[1] = *(const u32x2*)(p0 + 8);
      k1.d[0] = *(const u32x2*)p1;  k1.d[1] = *(const u32x2*)(p1 + 8);
      s0 = __builtin_amdgcn_mfma_f32_32x32x16_f16(k0.v, qf[cc], s0, 0, 0, 0);
      s1 = __builtin_amdgcn_mfma_f32_32x32x16_f16(k1.v, qf[cc], s1, 0, 0, 0);
    }
    __builtin_amdgcn_s_setprio(0);
    // P = exp2(S) (no max), tree row-sum
#pragma unroll
    for (int r = 0; r < 16; ++r) s0[r] = ex2(s0[r]);
#pragma unroll
    for (int r = 0; r < 16; ++r) s1[r] = ex2(s1[r]);
    {
      float p[16];
#pragma unroll
      for (int r = 0; r < 16; ++r) p[r] = s0[r] + s1[r];
#pragma unroll
      for (int d = 8; d >= 1; d >>= 1)
#pragma unroll
        for (int r = 0; r < d; ++r) p[r] += p[r + d];
      lacc += p[0];
    }
    // pack P -> bf16 A-fragments via cvt_pk + permlane32_swap
    unsigned c0[8], c1[8];
#pragma unroll
    for (int i = 0; i < 8; ++i) c0[i] = pk2bf(s0[2 * i], s0[2 * i + 1]);
#pragma unroll
    for (int i = 0; i < 8; ++i) c1[i] = pk2bf(s1[2 * i], s1[2 * i + 1]);
    PSWAP(c0[0], c0[2]); PSWAP(c0[1], c0[3]); PSWAP(c0[4], c0[6]); PSWAP(c0[5], c0[7]);
    PSWAP(c1[0], c1[2]); PSWAP(c1[1], c1[3]); PSWAP(c1[4], c1[6]); PSWAP(c1[5], c1[7]);
    union U8 { unsigned u[4]; bf16x8 v; } pa[4];
#pragma unroll
    for (int j = 0; j < 4; ++j) { pa[0].u[j] = c0[j]; pa[1].u[j] = c0[4 + j]; pa[2].u[j] = c1[j]; pa[3].u[j] = c1[4 + j]; }
    // PV: V row o at 8704 + o*136; o-block ot adds 4352 bytes each 32 rows
    __builtin_amdgcn_s_setprio(1);
#pragma unroll
    for (int kc = 0; kc < 4; ++kc) {
      const char* pv = bufp + 8704 + rb8[kc] * 8;
#pragma unroll
      for (int ot = 0; ot < 8; ++ot) {
        union { u32x2 d[2]; bf16x8 v; } vb;
        const char* p = pv + ot * 4352;
        vb.d[0] = *(const u32x2*)p;  vb.d[1] = *(const u32x2*)(p + 8);
        acc[ot] = __builtin_amdgcn_mfma_f32_32x32x16_bf16(pa[kc].v, vb.v, acc[ot], 0, 0, 0);
      }
    }
    __builtin_amdgcn_s_setprio(0);
    // tail: write next tile into the other buffer (overlaps other waves' compute)
    if (kt < 63) {
      *(u32x2*)(bufn + w8 * 8)              = u32x2{kreg[0], kreg[1]};
      *(u32x2*)(bufn + w8 * 8 + 8)          = u32x2{kreg[2], kreg[3]};
      *(u32x2*)(bufn + 8704  + w8 * 8)      = u32x2{vr0[0], vr0[1]};
      *(u32x2*)(bufn + 8704  + w8 * 8 + 8)  = u32x2{vr0[2], vr0[3]};
      *(u32x2*)(bufn + 17408 + w8 * 8)      = u32x2{vr1[0], vr1[1]};
      *(u32x2*)(bufn + 17408 + w8 * 8 + 8)  = u32x2{vr1[2], vr1[3]};
      *(u32x2*)(bufn + 26112 + w8 * 8)      = u32x2{vr2[0], vr2[1]};
      *(u32x2*)(bufn + 26112 + w8 * 8 + 8)  = u32x2{vr2[2], vr2[3]};
      *(u32x2*)(bufn + 34816 + w8 * 8)      = u32x2{vr3[0], vr3[1]};
      *(u32x2*)(bufn + 34816 + w8 * 8 + 8)  = u32x2{vr3[2], vr3[3]};
    }
  }
  // epilogue: l per q-row, scale = gamma/l; transpose 32x32 tiles via per-wave LDS; coalesced store
  float l_tot = lacc + __shfl_xor(lacc, 32);
  float sinv = gamma[0] / l_tot;
  __syncthreads();
  float* tb = (float*)smem + w * 1056;  // per-wave 32x33 f32
#pragma unroll
  for (int ot = 0; ot < 8; ++ot) {
#pragma unroll
    for (int r = 0; r < 16; ++r) {
      int qr = (r & 3) + 8 * (r >> 2) + 4 * hi;
      tb[ln * 33 + qr] = acc[ot][r];
    }
#pragma unroll
    for (int it = 0; it < 16; ++it) {
      int orow = it * 2 + hi;
      float v = tb[orow * 33 + ln];
      size_t gi = (((size_t)(b * 512 + obase + ot * 32 + orow)) << 12) + (size_t)(qt * 256 + w * 32 + ln);
      out[gi] = sinv * v + x[gi];
    }
    __syncthreads();
  }
}

extern "C" void kernel_launch(void* const* d_in, const int* in_sizes, int n_in,
                              void* d_out, int out_size, void* d_ws, size_t ws_size,
                              hipStream_t stream) {
  (void)in_sizes; (void)n_in; (void)out_size; (void)ws_size;
  const float* x     = (const float*)d_in[0];
  const float* wb    = (const float*)d_in[1];
  const float* wc    = (const float*)d_in[2];
  const float* wd    = (const float*)d_in[3];
  const float* gamma = (const float*)d_in[4];
  float* out = (float*)d_out;
  char* ws = (char*)d_ws;
  u16* xt  = (u16*)ws;                    // 32 MB: Xt f16 [B][N][C]
  u16* qkb = (u16*)(ws + 33554432);       //  8 MB: [B][N][Q(64)|K(64)] f16
  u16* vtb = (u16*)(ws + 41943040);       // 32 MB: V^T bf16 [B][C][N]
  k_tr   <<<dim3(4096), dim3(256), 0, stream>>>(x, xt);
  k_pqk  <<<dim3(256),  dim3(512), 0, stream>>>(xt, wb, wc, qkb);
  k_pv   <<<dim3(1024), dim3(512), 0, stream>>>(xt, wd, vtb);
  k_attn2<<<dim3(256),  dim3(512), 0, stream>>>(qkb, vtb, x, gamma, out);
}